// Round 6
// baseline (947.795 us; speedup 1.0000x reference)
//
#include <hip/hip_runtime.h>
#include <stdint.h>

typedef unsigned short u16;
typedef __attribute__((ext_vector_type(8))) short bf16x8;
typedef __attribute__((ext_vector_type(4))) float f32x4;

#define HD 256
#define AST 264       // A_lds row stride in u16 (528 B: 16B-aligned, bank-rotating)
#define CORR_CAP 2048 // backtracking-pair capacity (expected ~16 for this graph)

static __device__ __forceinline__ float b2f(u16 x){
  union{float f; unsigned u;} v; v.u = ((unsigned)x)<<16; return v.f;
}
static __device__ __forceinline__ u16 f2b(float f){
  union{float f; unsigned u;} v; v.f = f;
  unsigned r = v.u + 0x7fffu + ((v.u>>16)&1u);
  return (u16)(r>>16);
}
// accumulate relu(I + V) (both bf16 pairs) into a[4]
static __device__ __forceinline__ void racc2(float* a, uint2 iv, uint2 vv){
  float t0 = b2f((u16)iv.x)       + b2f((u16)vv.x);
  float t1 = b2f((u16)(iv.x>>16)) + b2f((u16)(vv.x>>16));
  float t2 = b2f((u16)iv.y)       + b2f((u16)vv.y);
  float t3 = b2f((u16)(iv.y>>16)) + b2f((u16)(vv.y>>16));
  a[0] += t0>0.f?t0:0.f; a[1] += t1>0.f?t1:0.f;
  a[2] += t2>0.f?t2:0.f; a[3] += t3>0.f?t3:0.f;
}
static __device__ __forceinline__ void racc1(float* a, uint2 iv){
  float t0 = b2f((u16)iv.x), t1 = b2f((u16)(iv.x>>16));
  float t2 = b2f((u16)iv.y), t3 = b2f((u16)(iv.y>>16));
  a[0] += t0>0.f?t0:0.f; a[1] += t1>0.f?t1:0.f;
  a[2] += t2>0.f?t2:0.f; a[3] += t3>0.f?t3:0.f;
}

// ---------------- zero int buffer ----------------
__global__ void k_zero_int(int* __restrict__ p, int n){
  int i = blockIdx.x*256 + threadIdx.x;
  if (i < n) p[i] = 0;
}

// ---------------- histogram ----------------
__global__ void k_hist(const int* __restrict__ key, int* __restrict__ deg, int n){
  int i = blockIdx.x*256 + threadIdx.x;
  if (i < n) atomicAdd(&deg[key[i]], 1);
}

// ---------------- 3-phase parallel exclusive scan ----------------
__global__ void k_scan_p1(const int* __restrict__ deg, int n, int* __restrict__ bsum){
  int i = blockIdx.x*256 + threadIdx.x;
  int v = (i < n) ? deg[i] : 0;
  #pragma unroll
  for (int o=32; o>0; o>>=1) v += __shfl_down(v, o);
  __shared__ int w[4];
  if ((threadIdx.x&63)==0) w[threadIdx.x>>6] = v;
  __syncthreads();
  if (threadIdx.x==0) bsum[blockIdx.x] = w[0]+w[1]+w[2]+w[3];
}
__global__ __launch_bounds__(1024) void k_scan_p2(int* __restrict__ bsum, int nb,
                                                  int* __restrict__ total_dst){
  __shared__ int sm[1024];
  int t = threadIdx.x;
  int v = (t < nb) ? bsum[t] : 0;
  sm[t] = v; __syncthreads();
  for (int o=1; o<1024; o<<=1){
    int u = (t>=o) ? sm[t-o] : 0;
    __syncthreads();
    sm[t] += u;
    __syncthreads();
  }
  if (t < nb) bsum[t] = sm[t] - v;
  if (t == 1023 && total_dst) *total_dst = sm[1023];
}
__global__ void k_scan_p3(const int* __restrict__ deg, const int* __restrict__ bsum, int n,
                          int* __restrict__ start, int* __restrict__ cursor){
  int t = threadIdx.x;
  int i = blockIdx.x*256 + t;
  int v = (i < n) ? deg[i] : 0;
  __shared__ int sm[256];
  sm[t] = v; __syncthreads();
  for (int o=1; o<256; o<<=1){
    int u = (t>=o) ? sm[t-o] : 0;
    __syncthreads();
    sm[t] += u;
    __syncthreads();
  }
  int ex = sm[t] - v + bsum[blockIdx.x];
  if (i < n){ start[i] = ex; cursor[i] = ex; }
}

// ---------------- fill buckets ----------------
__global__ void k_fill(const int* __restrict__ key, const int* __restrict__ val,
                       int* __restrict__ cursor, int* __restrict__ bucket, int n){
  int i = blockIdx.x*256 + threadIdx.x;
  if (i >= n) return;
  int pos = atomicAdd(&cursor[key[i]], 1);
  bucket[pos] = val ? val[i] : i;
}

// ---------------- permuted edge arrays (new label = dst-sorted rank) ----------------
__global__ void k_permarr(const int* __restrict__ perm, const int* __restrict__ esrc,
                          const int* __restrict__ edst, int* __restrict__ esrc_p,
                          int* __restrict__ edst_p, int E){
  int e = blockIdx.x*256 + threadIdx.x;
  if (e >= E) return;
  int o = perm[e];
  esrc_p[e] = esrc[o];
  edst_p[e] = edst[o];
}

// xep[e][5] = xe[perm[e]][5]
__global__ void k_xep(const float* __restrict__ xe, const int* __restrict__ perm,
                      float* __restrict__ xep, int E){
  int e = blockIdx.x*256 + threadIdx.x;
  if (e >= E) return;
  int o = perm[e];
  #pragma unroll
  for (int k=0;k<5;k++) xep[(size_t)e*5+k] = xe[(size_t)o*5+k];
}

// xnf[v][64] = [ xn[v] (35) | 0 pad ]  (bf16)
__global__ void k_xnf(const float* __restrict__ xn, u16* __restrict__ xnf, int N){
  int g = blockIdx.x*256 + threadIdx.x;
  int v2 = g >> 6, c = g & 63;
  if (v2 >= N) return;
  float v = (c < 35) ? xn[(size_t)v2*35 + c] : 0.f;
  xnf[g] = f2b(v);
}

// ---------------- alpha16[v] = bf16( sum_{j} tree_m[bucket[j]] ) ----------------
__global__ void k_alpha_gather(const float* __restrict__ tree_m, const int* __restrict__ start,
                               const int* __restrict__ bucket, u16* __restrict__ alpha16, int N){
  int v = (int)(((long long)blockIdx.x*blockDim.x + threadIdx.x)>>6);
  int l = threadIdx.x & 63;
  if (v >= N) return;
  int s = start[v], e2 = start[v+1];
  float a0=0.f,a1=0.f,a2=0.f,a3=0.f;
  for (int j=s;j<e2;j++){
    float4 tv = *(const float4*)(tree_m + (size_t)bucket[j]*HD + l*4);
    a0 += tv.x; a1 += tv.y; a2 += tv.z; a3 += tv.w;
  }
  ushort4 o; o.x=f2b(a0); o.y=f2b(a1); o.z=f2b(a2); o.w=f2b(a3);
  *(ushort4*)(alpha16 + (size_t)v*HD + l*4) = o;
}

// ---------------- generic frag-major B-table builder ----------------
__global__ void k_prep_frag(const float* __restrict__ W, int k0, int kmax, int nks,
                            u16* __restrict__ out){
  int g = blockIdx.x*256 + threadIdx.x;
  if (g >= nks*16*512) return;
  int i = g & 7, l = (g>>3)&63, t = g>>9;
  int nj = t & 15, ks = t >> 4;
  int n = nj*16 + (l&15);
  int k = ks*32 + (l>>4)*8 + i;
  float v = (k < kmax) ? W[(size_t)(k0+k)*HD + n] : 0.f;
  out[g] = f2b(v);
}

// ---------------- P/R GEMM: out = featA(64 cols) @ BTf (2 ksteps), raw linear ----------------
__global__ __launch_bounds__(512, 4) void k_pr_gemm(
    const u16* __restrict__ featA, const u16* __restrict__ BTf,
    u16* __restrict__ out16, int M)
{
  const int tid = threadIdx.x;
  const int w = tid>>6, l = tid&63;
  const int lr = l&15, lq = l>>4;
  const int nrb = (M+15)>>4;
  bf16x8 B0[2], B1[2];
  #pragma unroll
  for (int ks=0; ks<2; ks++){
    B0[ks] = *(const bf16x8*)(BTf + (size_t)((ks*16 + w*2  )*512) + l*8);
    B1[ks] = *(const bf16x8*)(BTf + (size_t)((ks*16 + w*2+1)*512) + l*8);
  }
  const int c0 = w*32 + lr, c1 = w*32 + 16 + lr;
  for (int rb = blockIdx.x; rb < nrb; rb += gridDim.x){
    int r = rb*16 + lr; int rc = min(r, M-1);
    const u16* fr = featA + (size_t)rc*64 + lq*8;
    bf16x8 a0 = *(const bf16x8*)(fr);
    bf16x8 a1 = *(const bf16x8*)(fr + 32);
    f32x4 acc0 = (f32x4){0.f,0.f,0.f,0.f};
    f32x4 acc1 = (f32x4){0.f,0.f,0.f,0.f};
    acc0 = __builtin_amdgcn_mfma_f32_16x16x32_bf16(a0, B0[0], acc0, 0,0,0);
    acc0 = __builtin_amdgcn_mfma_f32_16x16x32_bf16(a1, B0[1], acc0, 0,0,0);
    acc1 = __builtin_amdgcn_mfma_f32_16x16x32_bf16(a0, B1[0], acc1, 0,0,0);
    acc1 = __builtin_amdgcn_mfma_f32_16x16x32_bf16(a1, B1[1], acc1, 0,0,0);
    #pragma unroll
    for (int reg=0; reg<4; reg++){
      int gm = rb*16 + lq*4 + reg;
      if (gm < M){
        out16[(size_t)gm*HD + c0] = f2b(acc0[reg]);
        out16[(size_t)gm*HD + c1] = f2b(acc1[reg]);
      }
    }
  }
}

// ---------------- I[e] = P[src[e]] + xe[e]@Wi[35:40]  (pre-relu, bf16) ----------------
__global__ __launch_bounds__(256, 8) void k_build_I(
    const u16* __restrict__ P, const float* __restrict__ xep,
    const int* __restrict__ esrc_p, const float* __restrict__ Wi,
    u16* __restrict__ I, int E)
{
  const int l = threadIdx.x & 63;
  const int wid = (blockIdx.x*256 + threadIdx.x) >> 6;
  const int nw = gridDim.x*4;
  float wq[5][4];
  #pragma unroll
  for (int k=0;k<5;k++){
    float4 t = *(const float4*)(Wi + (size_t)(35+k)*HD + l*4);
    wq[k][0]=t.x; wq[k][1]=t.y; wq[k][2]=t.z; wq[k][3]=t.w;
  }
  for (int e = wid; e < E; e += nw){
    int s = esrc_p[e];
    const float* xp = xep + (size_t)e*5;
    float x0=xp[0], x1=xp[1], x2=xp[2], x3=xp[3], x4=xp[4];
    uint2 uv = *(const uint2*)(P + (size_t)s*HD + l*4);
    float v[4] = { b2f((u16)uv.x), b2f((u16)(uv.x>>16)),
                   b2f((u16)uv.y), b2f((u16)(uv.y>>16)) };
    #pragma unroll
    for (int j=0;j<4;j++)
      v[j] += x0*wq[0][j] + x1*wq[1][j] + x2*wq[2][j] + x3*wq[3][j] + x4*wq[4][j];
    ushort4 o; o.x=f2b(v[0]); o.y=f2b(v[1]); o.z=f2b(v[2]); o.w=f2b(v[3]);
    *(ushort4*)(I + (size_t)e*HD + l*4) = o;
  }
}

// ---------------- backtracking pair list (new labels; segments contiguous) ----------------
__global__ void k_pairs(const int* __restrict__ esrc_p, const int* __restrict__ edst_p,
                        const int* __restrict__ start_d,
                        int* __restrict__ npairs, int2* __restrict__ pairs, int E){
  int e = blockIdx.x*256 + threadIdx.x;
  if (e >= E) return;
  int u = esrc_p[e], v = edst_p[e];
  int s = start_d[u], t = start_d[u+1];
  for (int ep=s; ep<t; ep++){
    if (esrc_p[ep] == v){
      int pos = atomicAdd(npairs, 1);
      if (pos < CORR_CAP) pairs[pos] = (int2){e, ep};
    }
  }
}

// msgA[p] = relu(I[pairs[p].y])  (msg_0 of partner edges)
__global__ void k_msgA0(const u16* __restrict__ I, const int2* __restrict__ pairs,
                        const int* __restrict__ npairs_p, float* __restrict__ msgA){
  int np = *npairs_p; if (np > CORR_CAP) np = CORR_CAP;
  int t = threadIdx.x;
  for (int p = blockIdx.x; p < np; p += gridDim.x){
    int ep = pairs[p].y;
    float v = b2f(I[(size_t)ep*HD + t]);
    msgA[(size_t)p*HD + t] = v > 0.f ? v : 0.f;
  }
}

// ---------------- fused BP step: per node v ----------------
// S[v] = alpha[v] + sum_{in-edges e} relu(I[e] + Vprev[src[e]])   (Vprev NULL -> relu(I))
// mode 0: Vout[v] = S[v]@BTf (bf16)      mode 1: hout[v] = relu(Radd[v] + S[v]@BTf + bias)
__global__ __launch_bounds__(512, 4) void k_bp(
    const u16* __restrict__ I, const u16* __restrict__ Vprev,
    const u16* __restrict__ alpha16, const int* __restrict__ start_d,
    const int* __restrict__ esrc_p, const u16* __restrict__ BTf,
    const u16* __restrict__ Radd, const float* __restrict__ bias,
    u16* __restrict__ Sout, u16* __restrict__ Vout, float* __restrict__ hout,
    int N, int mode)
{
  __shared__ u16 A_lds[16][AST];   // 8448 B
  const int tid = threadIdx.x;
  const int w = tid>>6, l = tid&63;
  const int lr = l&15, lq = l>>4;
  const int ngrp = (N+15)>>4;

  bf16x8 B0[8], B1[8];
  #pragma unroll
  for (int ks=0; ks<8; ks++){
    B0[ks] = *(const bf16x8*)(BTf + (size_t)((ks*16 + w*2  )*512) + l*8);
    B1[ks] = *(const bf16x8*)(BTf + (size_t)((ks*16 + w*2+1)*512) + l*8);
  }
  const int c0 = w*32 + lr, c1 = w*32 + 16 + lr;
  float b0 = 0.f, b1 = 0.f;
  if (mode == 1){ b0 = bias[c0]; b1 = bias[c1]; }

  for (int grp = blockIdx.x; grp < ngrp; grp += gridDim.x){
    const int vb = grp*16;
    // ---- phase A: S = alpha + sum relu(I + Vgather); bf16 row -> LDS + global
    #pragma unroll
    for (int hh=0; hh<2; hh++){
      int v = vb + w*2 + hh;
      float a[4] = {0.f,0.f,0.f,0.f};
      if (v < N){
        uint2 av = *(const uint2*)(alpha16 + (size_t)v*HD + l*4);
        a[0]=b2f((u16)av.x); a[1]=b2f((u16)(av.x>>16));
        a[2]=b2f((u16)av.y); a[3]=b2f((u16)(av.y>>16));
        int s = start_d[v], e2 = start_d[v+1];
        int cnt = e2 - s;
        const u16* Ir = I + (size_t)s*HD + l*4;
        if (Vprev){
          const int* sp = esrc_p + s;
          int j = 0;
          for (; j+2 <= cnt; j+=2){
            int s0 = sp[j], s1 = sp[j+1];
            uint2 i0 = *(const uint2*)(Ir);
            uint2 i1 = *(const uint2*)(Ir + HD);
            uint2 v0 = *(const uint2*)(Vprev + (size_t)s0*HD + l*4);
            uint2 v1 = *(const uint2*)(Vprev + (size_t)s1*HD + l*4);
            Ir += 2*HD;
            racc2(a, i0, v0); racc2(a, i1, v1);
          }
          if (j < cnt){
            int s0 = sp[j];
            uint2 i0 = *(const uint2*)(Ir);
            uint2 v0 = *(const uint2*)(Vprev + (size_t)s0*HD + l*4);
            racc2(a, i0, v0);
          }
        } else {
          int j = 0;
          for (; j+2 <= cnt; j+=2){
            uint2 i0 = *(const uint2*)(Ir);
            uint2 i1 = *(const uint2*)(Ir + HD);
            Ir += 2*HD;
            racc1(a, i0); racc1(a, i1);
          }
          if (j < cnt) racc1(a, *(const uint2*)(Ir));
        }
      }
      ushort4 o; o.x=f2b(a[0]); o.y=f2b(a[1]); o.z=f2b(a[2]); o.w=f2b(a[3]);
      if (v < N) *(ushort4*)(Sout + (size_t)v*HD + l*4) = o;
      *(ushort4*)&A_lds[w*2+hh][l*4] = o;
    }
    __syncthreads();
    // ---- phase B: MFMA vs register B
    f32x4 acc0 = (f32x4){0.f,0.f,0.f,0.f};
    f32x4 acc1 = (f32x4){0.f,0.f,0.f,0.f};
    const u16* Ar = &A_lds[lr][0];
    #pragma unroll
    for (int ks=0; ks<8; ks++){
      bf16x8 af = *(const bf16x8*)(Ar + ks*32 + lq*8);
      acc0 = __builtin_amdgcn_mfma_f32_16x16x32_bf16(af, B0[ks], acc0, 0,0,0);
      acc1 = __builtin_amdgcn_mfma_f32_16x16x32_bf16(af, B1[ks], acc1, 0,0,0);
    }
    // ---- epilogue: col=c0/c1, row=lq*4+reg
    #pragma unroll
    for (int reg=0; reg<4; reg++){
      int gm = vb + lq*4 + reg;
      if (gm < N){
        if (mode == 1){
          float v0 = acc0[reg] + b2f(Radd[(size_t)gm*HD + c0]) + b0;
          float v1 = acc1[reg] + b2f(Radd[(size_t)gm*HD + c1]) + b1;
          hout[(size_t)gm*HD + c0] = v0 > 0.f ? v0 : 0.f;
          hout[(size_t)gm*HD + c1] = v1 > 0.f ? v1 : 0.f;
        } else {
          Vout[(size_t)gm*HD + c0] = f2b(acc0[reg]);
          Vout[(size_t)gm*HD + c1] = f2b(acc1[reg]);
        }
      }
    }
    __syncthreads();
  }
}

// ---------------- backtracking correction (single block; ~16 affected edges) ----------------
// pass1: per affected edge e: m_naive = relu(I+Vprev[src]) (bit-exact vs k_bp),
//        m_true = relu(I+Vprev[src] - C@Wh), C = sum of partner msgs (msgA);
//        Scur[dst[e]] += m_true - m_naive; newA for partner slots.
// pass2: recompute V (or h) rows for distinct affected dst nodes from corrected S.
__global__ __launch_bounds__(256, 1) void k_correct(
    const u16* __restrict__ I, const u16* __restrict__ Vprev,
    const int* __restrict__ esrc_p, const int* __restrict__ edst_p,
    const int2* __restrict__ pairs, const int* __restrict__ npairs_p,
    const float* __restrict__ Wh, u16* __restrict__ Scur,
    u16* __restrict__ Vcur, float* __restrict__ hout,
    const float* __restrict__ Wob, const u16* __restrict__ Radd,
    const float* __restrict__ bias,
    float* __restrict__ msgA, float* __restrict__ newA, int isfinal)
{
  int np = *npairs_p; if (np > CORR_CAP) np = CORR_CAP;
  if (np == 0) return;
  int t = threadIdx.x;
  __shared__ float cs[HD];
  __shared__ float sa[HD];
  // ---- pass 1
  for (int p=0; p<np; p++){
    int e = pairs[p].x;
    bool first = true;
    for (int q=0;q<p;q++) if (pairs[q].x == e){ first=false; break; }
    if (!first) continue;                    // uniform branch
    float c = 0.f;
    for (int q=p;q<np;q++) if (pairs[q].x == e) c += msgA[(size_t)q*HD + t];
    cs[t] = c; __syncthreads();
    float corr = 0.f;
    for (int k=0;k<HD;k++) corr += cs[k]*Wh[(size_t)k*HD + t];
    int u = esrc_p[e];
    float base = b2f(I[(size_t)e*HD + t]) + b2f(Vprev[(size_t)u*HD + t]);
    float mn = base > 0.f ? base : 0.f;
    float bt = base - corr;
    float mt = bt > 0.f ? bt : 0.f;
    int dv = edst_p[e];
    u16* sp2 = Scur + (size_t)dv*HD + t;
    *sp2 = f2b(b2f(*sp2) + mt - mn);
    for (int q=0;q<np;q++) if (pairs[q].y == e) newA[(size_t)q*HD + t] = mt;
    __syncthreads();
  }
  for (int p=0;p<np;p++) msgA[(size_t)p*HD + t] = newA[(size_t)p*HD + t];
  __syncthreads();
  // ---- pass 2: distinct affected dst nodes
  for (int p=0; p<np; p++){
    int dv = edst_p[pairs[p].x];
    bool first = true;
    for (int q=0;q<p;q++) if (edst_p[pairs[q].x] == dv){ first=false; break; }
    if (!first) continue;
    sa[t] = b2f(Scur[(size_t)dv*HD + t]);
    __syncthreads();
    if (!isfinal){
      float acc2 = 0.f;
      for (int k=0;k<HD;k++) acc2 += sa[k]*Wh[(size_t)k*HD + t];
      Vcur[(size_t)dv*HD + t] = f2b(acc2);
    } else {
      float acc2 = 0.f;
      for (int k=0;k<HD;k++) acc2 += sa[k]*Wob[(size_t)k*HD + t];
      float hv = acc2 + b2f(Radd[(size_t)dv*HD + t]) + bias[t];
      hout[(size_t)dv*HD + t] = hv > 0.f ? hv : 0.f;
    }
    __syncthreads();
  }
}

// ---------------- graph mean (graph_ids sorted), fp32 in/out ----------------
__global__ void k_graph_mean(const float* __restrict__ h, const int* __restrict__ gid,
                             int N, int G, float* __restrict__ out){
  int g = (int)(((long long)blockIdx.x*blockDim.x + threadIdx.x)>>6);
  int l = threadIdx.x & 63;
  if (g >= G) return;
  int lo=0, hi=N;
  while (lo<hi){ int mid=(lo+hi)>>1; if (gid[mid] < g) lo=mid+1; else hi=mid; }
  int b = lo;
  hi = N;
  while (lo<hi){ int mid=(lo+hi)>>1; if (gid[mid] < g+1) lo=mid+1; else hi=mid; }
  int e2 = lo;
  float a0=0.f,a1=0.f,a2=0.f,a3=0.f;
  for (int v=b; v<e2; v++){
    float4 hv = *(const float4*)(h + (size_t)v*HD + l*4);
    a0 += hv.x; a1 += hv.y; a2 += hv.z; a3 += hv.w;
  }
  int cnt = e2 - b; if (cnt < 1) cnt = 1;
  float inv = 1.0f/(float)cnt;
  float4 o; o.x=a0*inv; o.y=a1*inv; o.z=a2*inv; o.w=a3*inv;
  *(float4*)(out + (size_t)g*HD + l*4) = o;
}

extern "C" void kernel_launch(void* const* d_in, const int* in_sizes, int n_in,
                              void* d_out, int out_size, void* d_ws, size_t ws_size,
                              hipStream_t stream){
  const float* x_nodes = (const float*)d_in[0];
  const float* x_edges = (const float*)d_in[1];
  const float* tree_m  = (const float*)d_in[2];
  const float* W_i     = (const float*)d_in[3];
  const float* W_h     = (const float*)d_in[4];
  const float* W_o     = (const float*)d_in[5];
  const float* b_o     = (const float*)d_in[6];
  const int* edge_src = (const int*)d_in[7];
  const int* edge_dst = (const int*)d_in[8];
  const int* tgt      = (const int*)d_in[11];
  const int* teid     = (const int*)d_in[12];
  const int* gid      = (const int*)d_in[13];

  const int N = in_sizes[0]/35;
  const int E = in_sizes[1]/5;
  const int K = in_sizes[11];
  const int G = out_size/HD;

  // ---- workspace layout (~275 MB; fill showed ws >= 400 MB) ----
  char* wsb = (char*)d_ws;
  auto align256 = [](size_t x){ return (x + 255) & ~(size_t)255; };
  size_t oI      = 0;                                          // 102.4 MB
  size_t oSa     = oI      + align256((size_t)E*HD*2);         // 25.6 MB
  size_t oVa     = oSa     + align256((size_t)N*HD*2);         // 25.6 MB
  size_t oP      = oVa     + align256((size_t)N*HD*2);         // 25.6 MB (hbuf lo)
  size_t oVb     = oP      + align256((size_t)N*HD*2);         // 25.6 MB (hbuf hi)
  size_t oR      = oVb     + align256((size_t)N*HD*2);         // 25.6 MB
  size_t oAlpha  = oR      + align256((size_t)N*HD*2);         // 25.6 MB
  size_t oXnf    = oAlpha  + align256((size_t)N*HD*2);         // 6.4 MB
  size_t oXep    = oXnf    + align256((size_t)N*64*2);         // 4.0 MB
  size_t oBTP    = oXep    + align256((size_t)E*5*4);
  size_t oBTWh   = oBTP    + align256((size_t)2*16*512*2);
  size_t oBTRa   = oBTWh   + align256((size_t)8*16*512*2);
  size_t oBTWob  = oBTRa   + align256((size_t)2*16*512*2);
  size_t oDegD   = oBTWob  + align256((size_t)8*16*512*2);     // N+1 ints ([N]=npairs)
  size_t oStartD = oDegD   + align256((size_t)(N+1)*4);
  size_t oCurD   = oStartD + align256((size_t)(N+1)*4);
  size_t oPerm   = oCurD   + align256((size_t)N*4);
  size_t oEsrcP  = oPerm   + align256((size_t)E*4);
  size_t oEdstP  = oEsrcP  + align256((size_t)E*4);
  size_t oDegT   = oEdstP  + align256((size_t)E*4);
  size_t oStartT = oDegT   + align256((size_t)N*4);
  size_t oCurT   = oStartT + align256((size_t)(N+1)*4);
  size_t oBukT   = oCurT   + align256((size_t)N*4);
  size_t oBsum   = oBukT   + align256((size_t)K*4);
  size_t oPairs  = oBsum   + align256((size_t)1024*4);
  size_t oMsgA   = oPairs  + align256((size_t)CORR_CAP*8);     // 2 MB
  size_t oNewA   = oMsgA   + align256((size_t)CORR_CAP*HD*4);  // 2 MB

  u16*   I       = (u16*)(wsb + oI);
  u16*   Sa      = (u16*)(wsb + oSa);
  u16*   Va      = (u16*)(wsb + oVa);
  u16*   P       = (u16*)(wsb + oP);
  u16*   Vb      = (u16*)(wsb + oVb);
  u16*   R       = (u16*)(wsb + oR);
  u16*   alpha16 = (u16*)(wsb + oAlpha);
  u16*   xnf     = (u16*)(wsb + oXnf);
  float* xep     = (float*)(wsb + oXep);
  u16*   BT_P    = (u16*)(wsb + oBTP);
  u16*   BT_Wh   = (u16*)(wsb + oBTWh);
  u16*   BT_Ra   = (u16*)(wsb + oBTRa);
  u16*   BT_Wob  = (u16*)(wsb + oBTWob);
  int*   deg_d   = (int*)(wsb + oDegD);
  int*   npairs  = deg_d + N;                 // zeroed together with deg_d
  int*   start_d = (int*)(wsb + oStartD);
  int*   cur_d   = (int*)(wsb + oCurD);
  int*   perm    = (int*)(wsb + oPerm);
  int*   esrc_p  = (int*)(wsb + oEsrcP);
  int*   edst_p  = (int*)(wsb + oEdstP);
  int*   deg_t   = (int*)(wsb + oDegT);
  int*   start_t = (int*)(wsb + oStartT);
  int*   cur_t   = (int*)(wsb + oCurT);
  int*   buk_t   = (int*)(wsb + oBukT);
  int*   bsum    = (int*)(wsb + oBsum);
  int2*  pairs   = (int2*)(wsb + oPairs);
  float* msgA    = (float*)(wsb + oMsgA);
  float* newA    = (float*)(wsb + oNewA);
  // hbuf (N*HD fp32 = 51.2 MB) overlays P+Vb: P dead after build_I, Vb dead after call2
  float* hbuf    = (float*)(wsb + oP);

  const int egrid256 = (E+255)/256;
  const int kgrid256 = (K+255)/256;
  const int ngrid256 = (N+255)/256;
  const int nbN      = (N+255)/256;

  // ---- B tables
  k_prep_frag<<<64,  256, 0, stream>>>(W_i, 0, 35, 2, BT_P);
  k_prep_frag<<<256, 256, 0, stream>>>(W_h, 0, 256, 8, BT_Wh);
  k_prep_frag<<<64,  256, 0, stream>>>(W_o, 0, 35, 2, BT_Ra);
  k_prep_frag<<<256, 256, 0, stream>>>(W_o, 35, 256, 8, BT_Wob);

  // ---- dst-CSR -> edge permutation (new label = dst-sorted rank)
  k_zero_int<<<(N+1+255)/256, 256, 0, stream>>>(deg_d, N+1);
  k_hist<<<egrid256, 256, 0, stream>>>(edge_dst, deg_d, E);
  k_scan_p1<<<nbN, 256, 0, stream>>>(deg_d, N, bsum);
  k_scan_p2<<<1, 1024, 0, stream>>>(bsum, nbN, start_d + N);   // start_d[N] = E
  k_scan_p3<<<nbN, 256, 0, stream>>>(deg_d, bsum, N, start_d, cur_d);
  k_fill<<<egrid256, 256, 0, stream>>>(edge_dst, (const int*)0, cur_d, perm, E);
  k_permarr<<<egrid256, 256, 0, stream>>>(perm, edge_src, edge_dst, esrc_p, edst_p, E);
  k_xep<<<egrid256, 256, 0, stream>>>(x_edges, perm, xep, E);
  k_xnf<<<((size_t)N*64+255)/256, 256, 0, stream>>>(x_nodes, xnf, N);

  // ---- tgt-CSR + alpha gather
  k_zero_int<<<ngrid256, 256, 0, stream>>>(deg_t, N);
  k_hist<<<kgrid256, 256, 0, stream>>>(tgt, deg_t, K);
  k_scan_p1<<<nbN, 256, 0, stream>>>(deg_t, N, bsum);
  k_scan_p2<<<1, 1024, 0, stream>>>(bsum, nbN, start_t + N);   // start_t[N] = K
  k_scan_p3<<<nbN, 256, 0, stream>>>(deg_t, bsum, N, start_t, cur_t);
  k_fill<<<kgrid256, 256, 0, stream>>>(tgt, teid, cur_t, buk_t, K);
  k_alpha_gather<<<(N+3)/4, 256, 0, stream>>>(tree_m, start_t, buk_t, alpha16, N);

  k_pairs<<<egrid256, 256, 0, stream>>>(esrc_p, edst_p, start_d, npairs, pairs, E);

  // ---- P = xn@Wi_a, R = xn@Wo_a (raw linear, bf16)
  k_pr_gemm<<<512, 512, 0, stream>>>(xnf, BT_P, P, N);
  k_pr_gemm<<<512, 512, 0, stream>>>(xnf, BT_Ra, R, N);

  // ---- I = P[src] + xe@Wi_b (pre-relu); msgA = msg_0 of partner edges
  k_build_I<<<2048, 256, 0, stream>>>(P, xep, esrc_p, W_i, I, E);
  k_msgA0<<<64, 256, 0, stream>>>(I, pairs, npairs, msgA);

  const float* Wob = W_o + 35*HD;

  // ---- call0: S_0 = alpha + sum relu(I); V_0 = S_0@Wh  (msg_0 exact, no correction)
  k_bp<<<512, 512, 0, stream>>>(I, (const u16*)0, alpha16, start_d, esrc_p, BT_Wh,
                                (const u16*)0, (const float*)0, Sa, Va, (float*)0, N, 0);
  // ---- call1: V_0 -> V_1 (Vb), correct
  k_bp<<<512, 512, 0, stream>>>(I, Va, alpha16, start_d, esrc_p, BT_Wh,
                                (const u16*)0, (const float*)0, Sa, Vb, (float*)0, N, 0);
  k_correct<<<1, 256, 0, stream>>>(I, Va, esrc_p, edst_p, pairs, npairs, W_h, Sa,
                                   Vb, (float*)0, (const float*)0, (const u16*)0,
                                   (const float*)0, msgA, newA, 0);
  // ---- call2: V_1 -> V_2 (Va), correct
  k_bp<<<512, 512, 0, stream>>>(I, Vb, alpha16, start_d, esrc_p, BT_Wh,
                                (const u16*)0, (const float*)0, Sa, Va, (float*)0, N, 0);
  k_correct<<<1, 256, 0, stream>>>(I, Vb, esrc_p, edst_p, pairs, npairs, W_h, Sa,
                                   Va, (float*)0, (const float*)0, (const u16*)0,
                                   (const float*)0, msgA, newA, 0);
  // ---- call3 (final): h = relu(R + S_3@Wo_b + b), correct h rows
  k_bp<<<512, 512, 0, stream>>>(I, Va, alpha16, start_d, esrc_p, BT_Wob,
                                R, b_o, Sa, (u16*)0, hbuf, N, 1);
  k_correct<<<1, 256, 0, stream>>>(I, Va, esrc_p, edst_p, pairs, npairs, W_h, Sa,
                                   (u16*)0, hbuf, Wob, R, b_o, msgA, newA, 1);

  k_graph_mean<<<(G+3)/4, 256, 0, stream>>>(hbuf, gid, N, G, (float*)d_out);
}

// Round 7
// 674.868 us; speedup vs baseline: 1.4044x; 1.4044x over previous
//
#include <hip/hip_runtime.h>
#include <stdint.h>

typedef unsigned short u16;
typedef __attribute__((ext_vector_type(8))) short bf16x8;
typedef __attribute__((ext_vector_type(4))) float f32x4;

#define HD 256
#define AST 264       // A_lds row stride in u16 (528 B: 16B-aligned, bank-rotating)
#define CORR_CAP 2048 // backtracking-pair capacity (expected ~16 for this graph)

static __device__ __forceinline__ float b2f(u16 x){
  union{float f; unsigned u;} v; v.u = ((unsigned)x)<<16; return v.f;
}
static __device__ __forceinline__ u16 f2b(float f){
  union{float f; unsigned u;} v; v.f = f;
  unsigned r = v.u + 0x7fffu + ((v.u>>16)&1u);
  return (u16)(r>>16);
}
// accumulate relu(I + V) (both bf16 pairs) into a[4]
static __device__ __forceinline__ void racc2(float* a, uint2 iv, uint2 vv){
  float t0 = b2f((u16)iv.x)       + b2f((u16)vv.x);
  float t1 = b2f((u16)(iv.x>>16)) + b2f((u16)(vv.x>>16));
  float t2 = b2f((u16)iv.y)       + b2f((u16)vv.y);
  float t3 = b2f((u16)(iv.y>>16)) + b2f((u16)(vv.y>>16));
  a[0] += t0>0.f?t0:0.f; a[1] += t1>0.f?t1:0.f;
  a[2] += t2>0.f?t2:0.f; a[3] += t3>0.f?t3:0.f;
}
static __device__ __forceinline__ void racc1(float* a, uint2 iv){
  float t0 = b2f((u16)iv.x), t1 = b2f((u16)(iv.x>>16));
  float t2 = b2f((u16)iv.y), t3 = b2f((u16)(iv.y>>16));
  a[0] += t0>0.f?t0:0.f; a[1] += t1>0.f?t1:0.f;
  a[2] += t2>0.f?t2:0.f; a[3] += t3>0.f?t3:0.f;
}

// ---------------- zero int buffer ----------------
__global__ void k_zero_int(int* __restrict__ p, int n){
  int i = blockIdx.x*256 + threadIdx.x;
  if (i < n) p[i] = 0;
}

// ---------------- histogram ----------------
__global__ void k_hist(const int* __restrict__ key, int* __restrict__ deg, int n){
  int i = blockIdx.x*256 + threadIdx.x;
  if (i < n) atomicAdd(&deg[key[i]], 1);
}

// ---------------- 3-phase parallel exclusive scan ----------------
__global__ void k_scan_p1(const int* __restrict__ deg, int n, int* __restrict__ bsum){
  int i = blockIdx.x*256 + threadIdx.x;
  int v = (i < n) ? deg[i] : 0;
  #pragma unroll
  for (int o=32; o>0; o>>=1) v += __shfl_down(v, o);
  __shared__ int w[4];
  if ((threadIdx.x&63)==0) w[threadIdx.x>>6] = v;
  __syncthreads();
  if (threadIdx.x==0) bsum[blockIdx.x] = w[0]+w[1]+w[2]+w[3];
}
__global__ __launch_bounds__(1024) void k_scan_p2(int* __restrict__ bsum, int nb,
                                                  int* __restrict__ total_dst){
  __shared__ int sm[1024];
  int t = threadIdx.x;
  int v = (t < nb) ? bsum[t] : 0;
  sm[t] = v; __syncthreads();
  for (int o=1; o<1024; o<<=1){
    int u = (t>=o) ? sm[t-o] : 0;
    __syncthreads();
    sm[t] += u;
    __syncthreads();
  }
  if (t < nb) bsum[t] = sm[t] - v;
  if (t == 1023 && total_dst) *total_dst = sm[1023];
}
__global__ void k_scan_p3(const int* __restrict__ deg, const int* __restrict__ bsum, int n,
                          int* __restrict__ start, int* __restrict__ cursor){
  int t = threadIdx.x;
  int i = blockIdx.x*256 + t;
  int v = (i < n) ? deg[i] : 0;
  __shared__ int sm[256];
  sm[t] = v; __syncthreads();
  for (int o=1; o<256; o<<=1){
    int u = (t>=o) ? sm[t-o] : 0;
    __syncthreads();
    sm[t] += u;
    __syncthreads();
  }
  int ex = sm[t] - v + bsum[blockIdx.x];
  if (i < n){ start[i] = ex; cursor[i] = ex; }
}

// ---------------- fill buckets ----------------
__global__ void k_fill(const int* __restrict__ key, const int* __restrict__ val,
                       int* __restrict__ cursor, int* __restrict__ bucket, int n){
  int i = blockIdx.x*256 + threadIdx.x;
  if (i >= n) return;
  int pos = atomicAdd(&cursor[key[i]], 1);
  bucket[pos] = val ? val[i] : i;
}

// ---------------- permuted edge arrays (new label = dst-sorted rank) ----------------
__global__ void k_permarr(const int* __restrict__ perm, const int* __restrict__ esrc,
                          const int* __restrict__ edst, int* __restrict__ esrc_p,
                          int* __restrict__ edst_p, int E){
  int e = blockIdx.x*256 + threadIdx.x;
  if (e >= E) return;
  int o = perm[e];
  esrc_p[e] = esrc[o];
  edst_p[e] = edst[o];
}

// xep[e][5] = xe[perm[e]][5]
__global__ void k_xep(const float* __restrict__ xe, const int* __restrict__ perm,
                      float* __restrict__ xep, int E){
  int e = blockIdx.x*256 + threadIdx.x;
  if (e >= E) return;
  int o = perm[e];
  #pragma unroll
  for (int k=0;k<5;k++) xep[(size_t)e*5+k] = xe[(size_t)o*5+k];
}

// xnf[v][64] = [ xn[v] (35) | 0 pad ]  (bf16)
__global__ void k_xnf(const float* __restrict__ xn, u16* __restrict__ xnf, int N){
  int g = blockIdx.x*256 + threadIdx.x;
  int v2 = g >> 6, c = g & 63;
  if (v2 >= N) return;
  float v = (c < 35) ? xn[(size_t)v2*35 + c] : 0.f;
  xnf[g] = f2b(v);
}

// ---------------- alpha16[v] = bf16( sum_{j} tree_m[bucket[j]] ) ----------------
__global__ void k_alpha_gather(const float* __restrict__ tree_m, const int* __restrict__ start,
                               const int* __restrict__ bucket, u16* __restrict__ alpha16, int N){
  int v = (int)(((long long)blockIdx.x*blockDim.x + threadIdx.x)>>6);
  int l = threadIdx.x & 63;
  if (v >= N) return;
  int s = start[v], e2 = start[v+1];
  float a0=0.f,a1=0.f,a2=0.f,a3=0.f;
  for (int j=s;j<e2;j++){
    float4 tv = *(const float4*)(tree_m + (size_t)bucket[j]*HD + l*4);
    a0 += tv.x; a1 += tv.y; a2 += tv.z; a3 += tv.w;
  }
  ushort4 o; o.x=f2b(a0); o.y=f2b(a1); o.z=f2b(a2); o.w=f2b(a3);
  *(ushort4*)(alpha16 + (size_t)v*HD + l*4) = o;
}

// ---------------- generic frag-major B-table builder ----------------
__global__ void k_prep_frag(const float* __restrict__ W, int k0, int kmax, int nks,
                            u16* __restrict__ out){
  int g = blockIdx.x*256 + threadIdx.x;
  if (g >= nks*16*512) return;
  int i = g & 7, l = (g>>3)&63, t = g>>9;
  int nj = t & 15, ks = t >> 4;
  int n = nj*16 + (l&15);
  int k = ks*32 + (l>>4)*8 + i;
  float v = (k < kmax) ? W[(size_t)(k0+k)*HD + n] : 0.f;
  out[g] = f2b(v);
}

// ---------------- P/R GEMM: out = featA(64 cols) @ BTf (2 ksteps), raw linear ----------------
__global__ __launch_bounds__(512, 4) void k_pr_gemm(
    const u16* __restrict__ featA, const u16* __restrict__ BTf,
    u16* __restrict__ out16, int M)
{
  const int tid = threadIdx.x;
  const int w = tid>>6, l = tid&63;
  const int lr = l&15, lq = l>>4;
  const int nrb = (M+15)>>4;
  bf16x8 B0[2], B1[2];
  #pragma unroll
  for (int ks=0; ks<2; ks++){
    B0[ks] = *(const bf16x8*)(BTf + (size_t)((ks*16 + w*2  )*512) + l*8);
    B1[ks] = *(const bf16x8*)(BTf + (size_t)((ks*16 + w*2+1)*512) + l*8);
  }
  const int c0 = w*32 + lr, c1 = w*32 + 16 + lr;
  for (int rb = blockIdx.x; rb < nrb; rb += gridDim.x){
    int r = rb*16 + lr; int rc = min(r, M-1);
    const u16* fr = featA + (size_t)rc*64 + lq*8;
    bf16x8 a0 = *(const bf16x8*)(fr);
    bf16x8 a1 = *(const bf16x8*)(fr + 32);
    f32x4 acc0 = (f32x4){0.f,0.f,0.f,0.f};
    f32x4 acc1 = (f32x4){0.f,0.f,0.f,0.f};
    acc0 = __builtin_amdgcn_mfma_f32_16x16x32_bf16(a0, B0[0], acc0, 0,0,0);
    acc0 = __builtin_amdgcn_mfma_f32_16x16x32_bf16(a1, B0[1], acc0, 0,0,0);
    acc1 = __builtin_amdgcn_mfma_f32_16x16x32_bf16(a0, B1[0], acc1, 0,0,0);
    acc1 = __builtin_amdgcn_mfma_f32_16x16x32_bf16(a1, B1[1], acc1, 0,0,0);
    #pragma unroll
    for (int reg=0; reg<4; reg++){
      int gm = rb*16 + lq*4 + reg;
      if (gm < M){
        out16[(size_t)gm*HD + c0] = f2b(acc0[reg]);
        out16[(size_t)gm*HD + c1] = f2b(acc1[reg]);
      }
    }
  }
}

// ---------------- I[e] = P[src[e]] + xe[e]@Wi[35:40]  (pre-relu, bf16) ----------------
__global__ __launch_bounds__(256, 8) void k_build_I(
    const u16* __restrict__ P, const float* __restrict__ xep,
    const int* __restrict__ esrc_p, const float* __restrict__ Wi,
    u16* __restrict__ I, int E)
{
  const int l = threadIdx.x & 63;
  const int wid = (blockIdx.x*256 + threadIdx.x) >> 6;
  const int nw = gridDim.x*4;
  float wq[5][4];
  #pragma unroll
  for (int k=0;k<5;k++){
    float4 t = *(const float4*)(Wi + (size_t)(35+k)*HD + l*4);
    wq[k][0]=t.x; wq[k][1]=t.y; wq[k][2]=t.z; wq[k][3]=t.w;
  }
  for (int e = wid; e < E; e += nw){
    int s = esrc_p[e];
    const float* xp = xep + (size_t)e*5;
    float x0=xp[0], x1=xp[1], x2=xp[2], x3=xp[3], x4=xp[4];
    uint2 uv = *(const uint2*)(P + (size_t)s*HD + l*4);
    float v[4] = { b2f((u16)uv.x), b2f((u16)(uv.x>>16)),
                   b2f((u16)uv.y), b2f((u16)(uv.y>>16)) };
    #pragma unroll
    for (int j=0;j<4;j++)
      v[j] += x0*wq[0][j] + x1*wq[1][j] + x2*wq[2][j] + x3*wq[3][j] + x4*wq[4][j];
    ushort4 o; o.x=f2b(v[0]); o.y=f2b(v[1]); o.z=f2b(v[2]); o.w=f2b(v[3]);
    *(ushort4*)(I + (size_t)e*HD + l*4) = o;
  }
}

// ---------------- backtracking pair list (new labels; segments contiguous) ----------------
__global__ void k_pairs(const int* __restrict__ esrc_p, const int* __restrict__ edst_p,
                        const int* __restrict__ start_d,
                        int* __restrict__ npairs, int2* __restrict__ pairs, int E){
  int e = blockIdx.x*256 + threadIdx.x;
  if (e >= E) return;
  int u = esrc_p[e], v = edst_p[e];
  int s = start_d[u], t = start_d[u+1];
  for (int ep=s; ep<t; ep++){
    if (esrc_p[ep] == v){
      int pos = atomicAdd(npairs, 1);
      if (pos < CORR_CAP) pairs[pos] = (int2){e, ep};
    }
  }
}

// msgA[p] = relu(I[pairs[p].y])  (msg_0 of partner edges)
__global__ void k_msgA0(const u16* __restrict__ I, const int2* __restrict__ pairs,
                        const int* __restrict__ npairs_p, float* __restrict__ msgA){
  int np = *npairs_p; if (np > CORR_CAP) np = CORR_CAP;
  int t = threadIdx.x;
  for (int p = blockIdx.x; p < np; p += gridDim.x){
    int ep = pairs[p].y;
    float v = b2f(I[(size_t)ep*HD + t]);
    msgA[(size_t)p*HD + t] = v > 0.f ? v : 0.f;
  }
}

// ---------------- fused BP step: per node v ----------------
// S[v] = alpha[v] + sum_{in-edges e} relu(I[e] + Vprev[src[e]])   (Vprev NULL -> relu(I))
// mode 0: Vout[v] = S[v]@BTf (bf16)      mode 1: hout[v] = relu(Radd[v] + S[v]@BTf + bias)
__global__ __launch_bounds__(512, 4) void k_bp(
    const u16* __restrict__ I, const u16* __restrict__ Vprev,
    const u16* __restrict__ alpha16, const int* __restrict__ start_d,
    const int* __restrict__ esrc_p, const u16* __restrict__ BTf,
    const u16* __restrict__ Radd, const float* __restrict__ bias,
    u16* __restrict__ Sout, u16* __restrict__ Vout, float* __restrict__ hout,
    int N, int mode)
{
  __shared__ u16 A_lds[16][AST];   // 8448 B
  const int tid = threadIdx.x;
  const int w = tid>>6, l = tid&63;
  const int lr = l&15, lq = l>>4;
  const int ngrp = (N+15)>>4;

  bf16x8 B0[8], B1[8];
  #pragma unroll
  for (int ks=0; ks<8; ks++){
    B0[ks] = *(const bf16x8*)(BTf + (size_t)((ks*16 + w*2  )*512) + l*8);
    B1[ks] = *(const bf16x8*)(BTf + (size_t)((ks*16 + w*2+1)*512) + l*8);
  }
  const int c0 = w*32 + lr, c1 = w*32 + 16 + lr;
  float b0 = 0.f, b1 = 0.f;
  if (mode == 1){ b0 = bias[c0]; b1 = bias[c1]; }

  for (int grp = blockIdx.x; grp < ngrp; grp += gridDim.x){
    const int vb = grp*16;
    // ---- phase A: S = alpha + sum relu(I + Vgather); bf16 row -> LDS + global
    #pragma unroll
    for (int hh=0; hh<2; hh++){
      int v = vb + w*2 + hh;
      float a[4] = {0.f,0.f,0.f,0.f};
      if (v < N){
        uint2 av = *(const uint2*)(alpha16 + (size_t)v*HD + l*4);
        a[0]=b2f((u16)av.x); a[1]=b2f((u16)(av.x>>16));
        a[2]=b2f((u16)av.y); a[3]=b2f((u16)(av.y>>16));
        int s = start_d[v], e2 = start_d[v+1];
        int cnt = e2 - s;
        const u16* Ir = I + (size_t)s*HD + l*4;
        if (Vprev){
          const int* sp = esrc_p + s;
          int j = 0;
          for (; j+2 <= cnt; j+=2){
            int s0 = sp[j], s1 = sp[j+1];
            uint2 i0 = *(const uint2*)(Ir);
            uint2 i1 = *(const uint2*)(Ir + HD);
            uint2 v0 = *(const uint2*)(Vprev + (size_t)s0*HD + l*4);
            uint2 v1 = *(const uint2*)(Vprev + (size_t)s1*HD + l*4);
            Ir += 2*HD;
            racc2(a, i0, v0); racc2(a, i1, v1);
          }
          if (j < cnt){
            int s0 = sp[j];
            uint2 i0 = *(const uint2*)(Ir);
            uint2 v0 = *(const uint2*)(Vprev + (size_t)s0*HD + l*4);
            racc2(a, i0, v0);
          }
        } else {
          int j = 0;
          for (; j+2 <= cnt; j+=2){
            uint2 i0 = *(const uint2*)(Ir);
            uint2 i1 = *(const uint2*)(Ir + HD);
            Ir += 2*HD;
            racc1(a, i0); racc1(a, i1);
          }
          if (j < cnt) racc1(a, *(const uint2*)(Ir));
        }
      }
      ushort4 o; o.x=f2b(a[0]); o.y=f2b(a[1]); o.z=f2b(a[2]); o.w=f2b(a[3]);
      if (v < N) *(ushort4*)(Sout + (size_t)v*HD + l*4) = o;
      *(ushort4*)&A_lds[w*2+hh][l*4] = o;
    }
    __syncthreads();
    // ---- phase B: MFMA vs register B
    f32x4 acc0 = (f32x4){0.f,0.f,0.f,0.f};
    f32x4 acc1 = (f32x4){0.f,0.f,0.f,0.f};
    const u16* Ar = &A_lds[lr][0];
    #pragma unroll
    for (int ks=0; ks<8; ks++){
      bf16x8 af = *(const bf16x8*)(Ar + ks*32 + lq*8);
      acc0 = __builtin_amdgcn_mfma_f32_16x16x32_bf16(af, B0[ks], acc0, 0,0,0);
      acc1 = __builtin_amdgcn_mfma_f32_16x16x32_bf16(af, B1[ks], acc1, 0,0,0);
    }
    // ---- epilogue: col=c0/c1, row=lq*4+reg
    #pragma unroll
    for (int reg=0; reg<4; reg++){
      int gm = vb + lq*4 + reg;
      if (gm < N){
        if (mode == 1){
          float v0 = acc0[reg] + b2f(Radd[(size_t)gm*HD + c0]) + b0;
          float v1 = acc1[reg] + b2f(Radd[(size_t)gm*HD + c1]) + b1;
          hout[(size_t)gm*HD + c0] = v0 > 0.f ? v0 : 0.f;
          hout[(size_t)gm*HD + c1] = v1 > 0.f ? v1 : 0.f;
        } else {
          Vout[(size_t)gm*HD + c0] = f2b(acc0[reg]);
          Vout[(size_t)gm*HD + c1] = f2b(acc1[reg]);
        }
      }
    }
    __syncthreads();
  }
}

// ---------------- backtracking correction, parallel 3-phase ----------------
// corr1 (parallel over first-occurrence pairs): deltaS[p] = m_true - m_naive; newA = m_true
__global__ __launch_bounds__(256) void k_corr1(
    const u16* __restrict__ I, const u16* __restrict__ Vprev,
    const int* __restrict__ esrc_p,
    const int2* __restrict__ pairs, const int* __restrict__ npairs_p,
    const float* __restrict__ Wh, const float* __restrict__ msgA,
    float* __restrict__ newA, float* __restrict__ deltaS)
{
  int np = *npairs_p; if (np > CORR_CAP) np = CORR_CAP;
  int t = threadIdx.x;
  __shared__ float cs[HD];
  for (int p = blockIdx.x; p < np; p += gridDim.x){
    int e = pairs[p].x;
    bool first = true;                      // block-uniform
    for (int q=0;q<p;q++) if (pairs[q].x == e){ first=false; break; }
    __syncthreads();
    if (first){
      float c = 0.f;
      for (int q=p;q<np;q++) if (pairs[q].x == e) c += msgA[(size_t)q*HD + t];
      cs[t] = c;
    }
    __syncthreads();
    if (first){
      // ILP-unrolled dot: 4 independent chains so loads pipeline
      float a0=0.f,a1=0.f,a2=0.f,a3=0.f;
      for (int k=0;k<HD;k+=4){
        a0 += cs[k]  *Wh[(size_t)k*HD+t];
        a1 += cs[k+1]*Wh[(size_t)(k+1)*HD+t];
        a2 += cs[k+2]*Wh[(size_t)(k+2)*HD+t];
        a3 += cs[k+3]*Wh[(size_t)(k+3)*HD+t];
      }
      float corr = (a0+a1)+(a2+a3);
      int u = esrc_p[e];
      float base = b2f(I[(size_t)e*HD + t]) + b2f(Vprev[(size_t)u*HD + t]);
      float mn = base > 0.f ? base : 0.f;
      float bt = base - corr;
      float mt = bt > 0.f ? bt : 0.f;
      deltaS[(size_t)p*HD + t] = mt - mn;
      for (int q=0;q<np;q++) if (pairs[q].y == e) newA[(size_t)q*HD + t] = mt;
    }
  }
}

// corr2 (single tiny block): serially apply deltaS to Scur (handles shared dst); commit msgA
__global__ __launch_bounds__(256, 1) void k_corr2(
    const int2* __restrict__ pairs, const int* __restrict__ npairs_p,
    const int* __restrict__ edst_p, const float* __restrict__ deltaS,
    float* __restrict__ msgA, const float* __restrict__ newA,
    u16* __restrict__ Scur)
{
  int np = *npairs_p; if (np > CORR_CAP) np = CORR_CAP;
  int t = threadIdx.x;
  for (int p=0; p<np; p++){
    msgA[(size_t)p*HD + t] = newA[(size_t)p*HD + t];
    int e = pairs[p].x;
    bool first = true;
    for (int q=0;q<p;q++) if (pairs[q].x == e){ first=false; break; }
    if (first){
      int dv = edst_p[e];
      u16* sp = Scur + (size_t)dv*HD + t;
      *sp = f2b(b2f(*sp) + deltaS[(size_t)p*HD + t]);
    }
    __syncthreads();
  }
}

// corr3 (parallel over distinct affected dst): recompute V row (or h row) from corrected S
__global__ __launch_bounds__(256) void k_corr3(
    const int2* __restrict__ pairs, const int* __restrict__ npairs_p,
    const int* __restrict__ edst_p, const u16* __restrict__ Scur,
    const float* __restrict__ Wh, const float* __restrict__ Wob,
    const u16* __restrict__ Radd, const float* __restrict__ bias,
    u16* __restrict__ Vcur, float* __restrict__ hout, int isfinal)
{
  int np = *npairs_p; if (np > CORR_CAP) np = CORR_CAP;
  int t = threadIdx.x;
  __shared__ float sa[HD];
  for (int p = blockIdx.x; p < np; p += gridDim.x){
    int dv = edst_p[pairs[p].x];
    bool first = true;                      // block-uniform
    for (int q=0;q<p;q++) if (edst_p[pairs[q].x] == dv){ first=false; break; }
    __syncthreads();
    if (first) sa[t] = b2f(Scur[(size_t)dv*HD + t]);
    __syncthreads();
    if (first){
      const float* W = isfinal ? Wob : Wh;
      float a0=0.f,a1=0.f,a2=0.f,a3=0.f;
      for (int k=0;k<HD;k+=4){
        a0 += sa[k]  *W[(size_t)k*HD+t];
        a1 += sa[k+1]*W[(size_t)(k+1)*HD+t];
        a2 += sa[k+2]*W[(size_t)(k+2)*HD+t];
        a3 += sa[k+3]*W[(size_t)(k+3)*HD+t];
      }
      float acc = (a0+a1)+(a2+a3);
      if (isfinal){
        float hv = acc + b2f(Radd[(size_t)dv*HD + t]) + bias[t];
        hout[(size_t)dv*HD + t] = hv > 0.f ? hv : 0.f;
      } else {
        Vcur[(size_t)dv*HD + t] = f2b(acc);
      }
    }
  }
}

// ---------------- graph mean (graph_ids sorted), fp32 in/out ----------------
__global__ void k_graph_mean(const float* __restrict__ h, const int* __restrict__ gid,
                             int N, int G, float* __restrict__ out){
  int g = (int)(((long long)blockIdx.x*blockDim.x + threadIdx.x)>>6);
  int l = threadIdx.x & 63;
  if (g >= G) return;
  int lo=0, hi=N;
  while (lo<hi){ int mid=(lo+hi)>>1; if (gid[mid] < g) lo=mid+1; else hi=mid; }
  int b = lo;
  hi = N;
  while (lo<hi){ int mid=(lo+hi)>>1; if (gid[mid] < g+1) lo=mid+1; else hi=mid; }
  int e2 = lo;
  float a0=0.f,a1=0.f,a2=0.f,a3=0.f;
  for (int v=b; v<e2; v++){
    float4 hv = *(const float4*)(h + (size_t)v*HD + l*4);
    a0 += hv.x; a1 += hv.y; a2 += hv.z; a3 += hv.w;
  }
  int cnt = e2 - b; if (cnt < 1) cnt = 1;
  float inv = 1.0f/(float)cnt;
  float4 o; o.x=a0*inv; o.y=a1*inv; o.z=a2*inv; o.w=a3*inv;
  *(float4*)(out + (size_t)g*HD + l*4) = o;
}

extern "C" void kernel_launch(void* const* d_in, const int* in_sizes, int n_in,
                              void* d_out, int out_size, void* d_ws, size_t ws_size,
                              hipStream_t stream){
  const float* x_nodes = (const float*)d_in[0];
  const float* x_edges = (const float*)d_in[1];
  const float* tree_m  = (const float*)d_in[2];
  const float* W_i     = (const float*)d_in[3];
  const float* W_h     = (const float*)d_in[4];
  const float* W_o     = (const float*)d_in[5];
  const float* b_o     = (const float*)d_in[6];
  const int* edge_src = (const int*)d_in[7];
  const int* edge_dst = (const int*)d_in[8];
  const int* tgt      = (const int*)d_in[11];
  const int* teid     = (const int*)d_in[12];
  const int* gid      = (const int*)d_in[13];

  const int N = in_sizes[0]/35;
  const int E = in_sizes[1]/5;
  const int K = in_sizes[11];
  const int G = out_size/HD;

  // ---- workspace layout (~277 MB) ----
  char* wsb = (char*)d_ws;
  auto align256 = [](size_t x){ return (x + 255) & ~(size_t)255; };
  size_t oI      = 0;                                          // 102.4 MB
  size_t oSa     = oI      + align256((size_t)E*HD*2);         // 25.6 MB
  size_t oVa     = oSa     + align256((size_t)N*HD*2);         // 25.6 MB
  size_t oP      = oVa     + align256((size_t)N*HD*2);         // 25.6 MB (hbuf lo)
  size_t oVb     = oP      + align256((size_t)N*HD*2);         // 25.6 MB (hbuf hi)
  size_t oR      = oVb     + align256((size_t)N*HD*2);         // 25.6 MB
  size_t oAlpha  = oR      + align256((size_t)N*HD*2);         // 25.6 MB
  size_t oXnf    = oAlpha  + align256((size_t)N*HD*2);         // 6.4 MB
  size_t oXep    = oXnf    + align256((size_t)N*64*2);         // 4.0 MB
  size_t oBTP    = oXep    + align256((size_t)E*5*4);
  size_t oBTWh   = oBTP    + align256((size_t)2*16*512*2);
  size_t oBTRa   = oBTWh   + align256((size_t)8*16*512*2);
  size_t oBTWob  = oBTRa   + align256((size_t)2*16*512*2);
  size_t oDegD   = oBTWob  + align256((size_t)8*16*512*2);     // N+1 ints ([N]=npairs)
  size_t oStartD = oDegD   + align256((size_t)(N+1)*4);
  size_t oCurD   = oStartD + align256((size_t)(N+1)*4);
  size_t oPerm   = oCurD   + align256((size_t)N*4);
  size_t oEsrcP  = oPerm   + align256((size_t)E*4);
  size_t oEdstP  = oEsrcP  + align256((size_t)E*4);
  size_t oDegT   = oEdstP  + align256((size_t)E*4);
  size_t oStartT = oDegT   + align256((size_t)N*4);
  size_t oCurT   = oStartT + align256((size_t)(N+1)*4);
  size_t oBukT   = oCurT   + align256((size_t)N*4);
  size_t oBsum   = oBukT   + align256((size_t)K*4);
  size_t oPairs  = oBsum   + align256((size_t)1024*4);
  size_t oMsgA   = oPairs  + align256((size_t)CORR_CAP*8);     // 2 MB
  size_t oNewA   = oMsgA   + align256((size_t)CORR_CAP*HD*4);  // 2 MB
  size_t oDeltaS = oNewA   + align256((size_t)CORR_CAP*HD*4);  // 2 MB

  u16*   I       = (u16*)(wsb + oI);
  u16*   Sa      = (u16*)(wsb + oSa);
  u16*   Va      = (u16*)(wsb + oVa);
  u16*   P       = (u16*)(wsb + oP);
  u16*   Vb      = (u16*)(wsb + oVb);
  u16*   R       = (u16*)(wsb + oR);
  u16*   alpha16 = (u16*)(wsb + oAlpha);
  u16*   xnf     = (u16*)(wsb + oXnf);
  float* xep     = (float*)(wsb + oXep);
  u16*   BT_P    = (u16*)(wsb + oBTP);
  u16*   BT_Wh   = (u16*)(wsb + oBTWh);
  u16*   BT_Ra   = (u16*)(wsb + oBTRa);
  u16*   BT_Wob  = (u16*)(wsb + oBTWob);
  int*   deg_d   = (int*)(wsb + oDegD);
  int*   npairs  = deg_d + N;                 // zeroed together with deg_d
  int*   start_d = (int*)(wsb + oStartD);
  int*   cur_d   = (int*)(wsb + oCurD);
  int*   perm    = (int*)(wsb + oPerm);
  int*   esrc_p  = (int*)(wsb + oEsrcP);
  int*   edst_p  = (int*)(wsb + oEdstP);
  int*   deg_t   = (int*)(wsb + oDegT);
  int*   start_t = (int*)(wsb + oStartT);
  int*   cur_t   = (int*)(wsb + oCurT);
  int*   buk_t   = (int*)(wsb + oBukT);
  int*   bsum    = (int*)(wsb + oBsum);
  int2*  pairs   = (int2*)(wsb + oPairs);
  float* msgA    = (float*)(wsb + oMsgA);
  float* newA    = (float*)(wsb + oNewA);
  float* deltaS  = (float*)(wsb + oDeltaS);
  // hbuf (N*HD fp32 = 51.2 MB) overlays P+Vb: P dead after build_I, Vb dead after call2
  float* hbuf    = (float*)(wsb + oP);

  const int egrid256 = (E+255)/256;
  const int kgrid256 = (K+255)/256;
  const int ngrid256 = (N+255)/256;
  const int nbN      = (N+255)/256;

  // ---- B tables
  k_prep_frag<<<64,  256, 0, stream>>>(W_i, 0, 35, 2, BT_P);
  k_prep_frag<<<256, 256, 0, stream>>>(W_h, 0, 256, 8, BT_Wh);
  k_prep_frag<<<64,  256, 0, stream>>>(W_o, 0, 35, 2, BT_Ra);
  k_prep_frag<<<256, 256, 0, stream>>>(W_o, 35, 256, 8, BT_Wob);

  // ---- dst-CSR -> edge permutation (new label = dst-sorted rank)
  k_zero_int<<<(N+1+255)/256, 256, 0, stream>>>(deg_d, N+1);
  k_hist<<<egrid256, 256, 0, stream>>>(edge_dst, deg_d, E);
  k_scan_p1<<<nbN, 256, 0, stream>>>(deg_d, N, bsum);
  k_scan_p2<<<1, 1024, 0, stream>>>(bsum, nbN, start_d + N);   // start_d[N] = E
  k_scan_p3<<<nbN, 256, 0, stream>>>(deg_d, bsum, N, start_d, cur_d);
  k_fill<<<egrid256, 256, 0, stream>>>(edge_dst, (const int*)0, cur_d, perm, E);
  k_permarr<<<egrid256, 256, 0, stream>>>(perm, edge_src, edge_dst, esrc_p, edst_p, E);
  k_xep<<<egrid256, 256, 0, stream>>>(x_edges, perm, xep, E);
  k_xnf<<<((size_t)N*64+255)/256, 256, 0, stream>>>(x_nodes, xnf, N);

  // ---- tgt-CSR + alpha gather
  k_zero_int<<<ngrid256, 256, 0, stream>>>(deg_t, N);
  k_hist<<<kgrid256, 256, 0, stream>>>(tgt, deg_t, K);
  k_scan_p1<<<nbN, 256, 0, stream>>>(deg_t, N, bsum);
  k_scan_p2<<<1, 1024, 0, stream>>>(bsum, nbN, start_t + N);   // start_t[N] = K
  k_scan_p3<<<nbN, 256, 0, stream>>>(deg_t, bsum, N, start_t, cur_t);
  k_fill<<<kgrid256, 256, 0, stream>>>(tgt, teid, cur_t, buk_t, K);
  k_alpha_gather<<<(N+3)/4, 256, 0, stream>>>(tree_m, start_t, buk_t, alpha16, N);

  k_pairs<<<egrid256, 256, 0, stream>>>(esrc_p, edst_p, start_d, npairs, pairs, E);

  // ---- P = xn@Wi_a, R = xn@Wo_a (raw linear, bf16)
  k_pr_gemm<<<512, 512, 0, stream>>>(xnf, BT_P, P, N);
  k_pr_gemm<<<512, 512, 0, stream>>>(xnf, BT_Ra, R, N);

  // ---- I = P[src] + xe@Wi_b (pre-relu); msgA = msg_0 of partner edges
  k_build_I<<<2048, 256, 0, stream>>>(P, xep, esrc_p, W_i, I, E);
  k_msgA0<<<64, 256, 0, stream>>>(I, pairs, npairs, msgA);

  const float* Wob = W_o + 35*HD;

  // ---- call0: S_0 = alpha + sum relu(I); V_0 = S_0@Wh  (msg_0 exact, no correction)
  k_bp<<<1024, 512, 0, stream>>>(I, (const u16*)0, alpha16, start_d, esrc_p, BT_Wh,
                                 (const u16*)0, (const float*)0, Sa, Va, (float*)0, N, 0);
  // ---- call1: V_0 -> V_1 (Vb), correct
  k_bp<<<1024, 512, 0, stream>>>(I, Va, alpha16, start_d, esrc_p, BT_Wh,
                                 (const u16*)0, (const float*)0, Sa, Vb, (float*)0, N, 0);
  k_corr1<<<64, 256, 0, stream>>>(I, Va, esrc_p, pairs, npairs, W_h, msgA, newA, deltaS);
  k_corr2<<<1, 256, 0, stream>>>(pairs, npairs, edst_p, deltaS, msgA, newA, Sa);
  k_corr3<<<64, 256, 0, stream>>>(pairs, npairs, edst_p, Sa, W_h, Wob,
                                  (const u16*)0, (const float*)0, Vb, (float*)0, 0);
  // ---- call2: V_1 -> V_2 (Va), correct
  k_bp<<<1024, 512, 0, stream>>>(I, Vb, alpha16, start_d, esrc_p, BT_Wh,
                                 (const u16*)0, (const float*)0, Sa, Va, (float*)0, N, 0);
  k_corr1<<<64, 256, 0, stream>>>(I, Vb, esrc_p, pairs, npairs, W_h, msgA, newA, deltaS);
  k_corr2<<<1, 256, 0, stream>>>(pairs, npairs, edst_p, deltaS, msgA, newA, Sa);
  k_corr3<<<64, 256, 0, stream>>>(pairs, npairs, edst_p, Sa, W_h, Wob,
                                  (const u16*)0, (const float*)0, Va, (float*)0, 0);
  // ---- call3 (final): h = relu(R + S_3@Wo_b + b), correct h rows
  k_bp<<<1024, 512, 0, stream>>>(I, Va, alpha16, start_d, esrc_p, BT_Wob,
                                 R, b_o, Sa, (u16*)0, hbuf, N, 1);
  k_corr1<<<64, 256, 0, stream>>>(I, Va, esrc_p, pairs, npairs, W_h, msgA, newA, deltaS);
  k_corr2<<<1, 256, 0, stream>>>(pairs, npairs, edst_p, deltaS, msgA, newA, Sa);
  k_corr3<<<64, 256, 0, stream>>>(pairs, npairs, edst_p, Sa, W_h, Wob,
                                  R, b_o, (u16*)0, hbuf, 1);

  k_graph_mean<<<(G+3)/4, 256, 0, stream>>>(hbuf, gid, N, G, (float*)d_out);
}